// Round 16
// baseline (263.343 us; speedup 1.0000x reference)
//
#include <hip/hip_runtime.h>

#define KN 100000
#define KE 1600000
#define KD 128
#define NBKT 768    // node buckets: 3 * 256 CUs, all co-resident at 3 blocks/CU
#define NPB 131     // nodes per bucket: 768*131 = 100608 >= 100000; fits 8 bits
#define NBLKE 391   // edge blocks of EPB (scatter role)
#define NCVT 782    // convert-role blocks
#define EPB 4096
#define SRTCAP 2560 // fixed slot per bucket (mean 2083, ~10 sigma headroom)

typedef __bf16 bf16;
typedef __attribute__((ext_vector_type(8))) __bf16 bf16x8;
typedef __attribute__((ext_vector_type(4))) __bf16 bf16x4;
typedef __attribute__((ext_vector_type(4))) float f32x4;
typedef __attribute__((ext_vector_type(2))) float f32x2;

// ---------------- ws layout (bytes) ----------------
// usf8   @ 0        : KN*128 fp8 (12.8 MB)
// usb    @ 25600000 : KN*128 bf16 (25.6 MB)
// packed @ 51600000 : NBKT*SRTCAP i32 (7.86 MB), fixed slot per bucket
// gcur   @ 59464320 : NBKT i32
// Wb     @ 59467392 : 128*256 bf16 (64 KB), j-major [W_self|W_neigh]

__device__ inline unsigned enc_fp8x4(float4 v) {
    int r = 0;
    r = __builtin_amdgcn_cvt_pk_fp8_f32(v.x, v.y, r, false);
    r = __builtin_amdgcn_cvt_pk_fp8_f32(v.z, v.w, r, true);
    return (unsigned)r;
}
template <bool HI>
__device__ inline f32x2 dec_fp8x2(unsigned u) {
    return __builtin_amdgcn_cvt_pk_f32_fp8((int)u, HI);
}

// Heterogeneous grid: blocks [0,391) scatter edges into fixed bucket slots;
// blocks [391,1173) stream-convert us -> usb (bf16) + usf8 (fp8) (+ Wb slice).
__launch_bounds__(512)
__global__ void prepscat_kernel(const float* __restrict__ us, bf16* __restrict__ usb,
                                unsigned* __restrict__ usf8, const int* __restrict__ src,
                                const int* __restrict__ dst, int* __restrict__ gcur,
                                int* __restrict__ packed, const float* __restrict__ Ws,
                                const float* __restrict__ Wn, bf16* __restrict__ Wb) {
    const int t = threadIdx.x, bb = blockIdx.x;
    if (bb >= NBLKE) {
        // ---- convert path (cb = 0..781) ----
        const int cb = bb - NBLKE;
        int wi = cb * 512 + t;  // W: 32768 elems over first 64 convert blocks
        if (wi < KD * 256) {
            int j = wi >> 8, k = wi & 255;
            float v = (k < KD) ? Ws[j * KD + k] : Wn[j * KD + (k - KD)];
            Wb[wi] = (bf16)v;
        }
        for (int i = cb * 512 + t; i < KN * KD / 4; i += NCVT * 512) {
            float4 v = reinterpret_cast<const float4*>(us)[i];
            bf16x4 o = {(bf16)v.x, (bf16)v.y, (bf16)v.z, (bf16)v.w};
            reinterpret_cast<bf16x4*>(usb)[i] = o;
            usf8[i] = enc_fp8x4(v);
        }
        return;
    }
    // ---- scatter path (b = 0..390) ----
    const int b = bb;
    __shared__ int h[NBKT];
    __shared__ int base[NBKT];
    for (int j = t; j < NBKT; j += 512) h[j] = 0;
    __syncthreads();
    const int e0 = b * EPB;
    int sv[8];
#pragma unroll
    for (int i = 0; i < 8; ++i) {
        int e = e0 + i * 512 + t;
        sv[i] = (e < KE) ? src[e] : -1;
        if (sv[i] >= 0) atomicAdd(&h[(unsigned)sv[i] / NPB], 1);
    }
    __syncthreads();
    for (int j = t; j < NBKT; j += 512) {
        int c = h[j];
        base[j] = (c > 0) ? (j * SRTCAP + atomicAdd(&gcur[j], c)) : 0;
        h[j] = 0;  // reuse as scatter cursor
    }
    __syncthreads();
#pragma unroll
    for (int i = 0; i < 8; ++i) {
        if (sv[i] >= 0) {
            int e = e0 + i * 512 + t;
            int d = dst[e];
            unsigned j = (unsigned)sv[i] / NPB;
            int sl = sv[i] - (int)j * NPB;
            int r = atomicAdd(&h[j], 1);
            int p = base[j] + r;
            if (p < (int)(j + 1) * SRTCAP) packed[p] = (d << 8) | sl;
        }
    }
}

// One block (512 thr) per 131-node bucket.
// phase 1: LDS counting-sort by src_low (packed read once into regs)
// phase 2: fp8 gather-aggregate, 16-edge unroll (8 outstanding 16B loads/lane)
// phase 3: MFMA gemm, A-self direct from global, A-mean from swizzled LDS.
__launch_bounds__(512, 6)
__global__ void sortfused_kernel(const unsigned* __restrict__ usf8,
                                 const bf16* __restrict__ usb,
                                 const int* __restrict__ packed,
                                 const int* __restrict__ gcur,
                                 const bf16* __restrict__ Wb,
                                 const float* __restrict__ b_self,
                                 const float* __restrict__ b_neigh,
                                 float* __restrict__ out) {
    __shared__ bf16 meanls[NPB * 128];   // 33536 B, granule-swizzled
    __shared__ float flls[NPB];
    __shared__ int srt[SRTCAP];          // 10240 B
    __shared__ int h[132], scn[132], off[132], cur[132];

    const int t = threadIdx.x, b = blockIdx.x;
    const int n0 = b * NPB;
    const int E0 = b * SRTCAP;
    int E = gcur[b];
    if (E > SRTCAP) E = SRTCAP;

    // ---------- phase 1: counting sort (packed read once into regs) ----------
    if (t < NPB) { h[t] = 0; cur[t] = 0; }
    __syncthreads();
    int v0 = -1, v1 = -1, v2 = -1, v3 = -1, v4 = -1;
    if (t < E) v0 = packed[E0 + t];
    if (t + 512 < E) v1 = packed[E0 + t + 512];
    if (t + 1024 < E) v2 = packed[E0 + t + 1024];
    if (t + 1536 < E) v3 = packed[E0 + t + 1536];
    if (t + 2048 < E) v4 = packed[E0 + t + 2048];
    if (v0 >= 0) atomicAdd(&h[v0 & 255], 1);
    if (v1 >= 0) atomicAdd(&h[v1 & 255], 1);
    if (v2 >= 0) atomicAdd(&h[v2 & 255], 1);
    if (v3 >= 0) atomicAdd(&h[v3 & 255], 1);
    if (v4 >= 0) atomicAdd(&h[v4 & 255], 1);
    __syncthreads();
    if (t < NPB) scn[t] = h[t];
    __syncthreads();
    for (int o2 = 1; o2 < NPB; o2 <<= 1) {
        int x = 0;
        if (t < NPB && t >= o2) x = scn[t - o2];
        __syncthreads();
        if (t < NPB) scn[t] += x;
        __syncthreads();
    }
    if (t < NPB) off[t] = scn[t] - h[t];
    __syncthreads();
#define SCAT(vk)                                             \
    if (vk >= 0) {                                           \
        int sl_ = vk & 255;                                  \
        int r_ = atomicAdd(&cur[sl_], 1);                    \
        int p_ = off[sl_] + r_;                              \
        if (p_ < SRTCAP) srt[p_] = vk >> 8;                  \
    }
    SCAT(v0)
    SCAT(v1)
    SCAT(v2)
    SCAT(v3)
    SCAT(v4)
#undef SCAT
    __syncthreads();

    // ---------- phase 2: gather-aggregate into swizzled meanls ----------
    const int lane = t & 63, w = t >> 6;           // 8 waves
    const int gid = (w << 2) + ((lane >> 4) & 3);  // 16-lane group 0..31
    const int sub = (lane >> 3) & 1;               // edge-slot parity
    const int sl = lane & 7;                       // 16B chunk: cols sl*16..+15
    const uint4* __restrict__ u4 = reinterpret_cast<const uint4*>(usf8);

#define ACC16(Q)                                                          \
    {                                                                     \
        f32x2 p;                                                          \
        p = dec_fp8x2<false>(Q.x); a[0] += p[0];  a[1] += p[1];           \
        p = dec_fp8x2<true>(Q.x);  a[2] += p[0];  a[3] += p[1];           \
        p = dec_fp8x2<false>(Q.y); a[4] += p[0];  a[5] += p[1];           \
        p = dec_fp8x2<true>(Q.y);  a[6] += p[0];  a[7] += p[1];           \
        p = dec_fp8x2<false>(Q.z); a[8] += p[0];  a[9] += p[1];           \
        p = dec_fp8x2<true>(Q.z);  a[10] += p[0]; a[11] += p[1];          \
        p = dec_fp8x2<false>(Q.w); a[12] += p[0]; a[13] += p[1];          \
        p = dec_fp8x2<true>(Q.w);  a[14] += p[0]; a[15] += p[1];          \
    }

#pragma unroll 1
    for (int it = 0; it < 5; ++it) {
        int nl = it * 32 + gid;  // 0..159
        bool valid = (nl < NPB) && (n0 + nl < KN);
        int cnt = valid ? h[nl] : 0;
        int o = valid ? off[nl] : 0;
        float a[16];
#pragma unroll
        for (int j = 0; j < 16; ++j) a[j] = 0.f;
        int e = 0;
        for (; e + 16 <= cnt; e += 16) {  // 8 outstanding 16B loads per lane
            int d0 = srt[o + e + sub];
            int d1 = srt[o + e + 2 + sub];
            int d2 = srt[o + e + 4 + sub];
            int d3 = srt[o + e + 6 + sub];
            int d4 = srt[o + e + 8 + sub];
            int d5 = srt[o + e + 10 + sub];
            int d6 = srt[o + e + 12 + sub];
            int d7 = srt[o + e + 14 + sub];
            uint4 q0 = u4[(size_t)d0 * 8 + sl];
            uint4 q1 = u4[(size_t)d1 * 8 + sl];
            uint4 q2 = u4[(size_t)d2 * 8 + sl];
            uint4 q3 = u4[(size_t)d3 * 8 + sl];
            uint4 q4 = u4[(size_t)d4 * 8 + sl];
            uint4 q5 = u4[(size_t)d5 * 8 + sl];
            uint4 q6 = u4[(size_t)d6 * 8 + sl];
            uint4 q7 = u4[(size_t)d7 * 8 + sl];
            ACC16(q0);
            ACC16(q1);
            ACC16(q2);
            ACC16(q3);
            ACC16(q4);
            ACC16(q5);
            ACC16(q6);
            ACC16(q7);
        }
        for (; e + 8 <= cnt; e += 8) {
            int d0 = srt[o + e + sub];
            int d1 = srt[o + e + 2 + sub];
            int d2 = srt[o + e + 4 + sub];
            int d3 = srt[o + e + 6 + sub];
            uint4 q0 = u4[(size_t)d0 * 8 + sl];
            uint4 q1 = u4[(size_t)d1 * 8 + sl];
            uint4 q2 = u4[(size_t)d2 * 8 + sl];
            uint4 q3 = u4[(size_t)d3 * 8 + sl];
            ACC16(q0);
            ACC16(q1);
            ACC16(q2);
            ACC16(q3);
        }
        for (; e < cnt; e += 2) {
            if (e + sub < cnt) {
                int d0 = srt[o + e + sub];
                uint4 q0 = u4[(size_t)d0 * 8 + sl];
                ACC16(q0);
            }
        }
#pragma unroll
        for (int j = 0; j < 16; ++j) a[j] += __shfl_xor(a[j], 8);
        if ((nl < NPB) && sub == 0) {
            float rc = (cnt > 0) ? 1.0f / (float)cnt : 0.0f;
            bf16x8 o0, o1;
#pragma unroll
            for (int j = 0; j < 8; ++j) {
                o0[j] = (bf16)(a[j] * rc);
                o1[j] = (bf16)(a[j + 8] * rc);
            }
            int G0 = (sl * 2) ^ (nl & 7);
            int G1 = (sl * 2 + 1) ^ (nl & 7);
            *reinterpret_cast<bf16x8*>(&meanls[nl * 128 + (G0 << 3)]) = o0;
            *reinterpret_cast<bf16x8*>(&meanls[nl * 128 + (G1 << 3)]) = o1;
            if (sl == 0) flls[nl] = (cnt > 0) ? 1.0f : 0.0f;
        }
    }
#undef ACC16
    __syncthreads();

    // ---------- phase 3: MFMA gemm ----------
    const int lr = lane & 15;
    const int g = lane >> 4;
    bf16x8 Bf[8];
    {
        const bf16* wp = Wb + (size_t)(w * 16 + lr) * 256 + g * 8;
#pragma unroll
        for (int ch = 0; ch < 8; ++ch) Bf[ch] = *reinterpret_cast<const bf16x8*>(wp + ch * 32);
    }
    const float bs = b_self[w * 16 + lr];
    const float bn = b_neigh[w * 16 + lr];

#pragma unroll 1
    for (int rt = 0; rt < 9; ++rt) {
        f32x4 acc = {0.f, 0.f, 0.f, 0.f};
        const int arow = rt * 16 + lr;
        const int mrow = (arow < NPB) ? arow : (NPB - 1);
        int na = n0 + arow;
        if (na >= KN) na = KN - 1;
        const bf16* apu = usb + (size_t)na * KD + g * 8;
        const int mswz = mrow & 7;
        const bf16* apm = &meanls[mrow * 128];
#pragma unroll
        for (int ch = 0; ch < 4; ++ch) {
            bf16x8 af = *reinterpret_cast<const bf16x8*>(apu + ch * 32);
            acc = __builtin_amdgcn_mfma_f32_16x16x32_bf16(af, Bf[ch], acc, 0, 0, 0);
        }
#pragma unroll
        for (int ch = 0; ch < 4; ++ch) {
            int G = (g + 4 * ch) ^ mswz;
            bf16x8 af = *reinterpret_cast<const bf16x8*>(apm + (G << 3));
            acc = __builtin_amdgcn_mfma_f32_16x16x32_bf16(af, Bf[ch + 4], acc, 0, 0, 0);
        }
#pragma unroll
        for (int r = 0; r < 4; ++r) {
            int rowg = rt * 16 + g * 4 + r;
            int n = n0 + rowg;
            if (rowg < NPB && n < KN) {
                float f = flls[rowg];
                out[(size_t)n * KD + w * 16 + lr] = fmaxf(acc[r] + bs + f * bn, 0.0f);
            }
        }
    }
}

extern "C" void kernel_launch(void* const* d_in, const int* in_sizes, int n_in,
                              void* d_out, int out_size, void* d_ws, size_t ws_size,
                              hipStream_t stream) {
    const float* us     = (const float*)d_in[0];
    const int*   src    = (const int*)d_in[1];
    const int*   dst    = (const int*)d_in[2];
    const float* Wself  = (const float*)d_in[3];
    const float* bself  = (const float*)d_in[4];
    const float* Wneigh = (const float*)d_in[5];
    const float* bneigh = (const float*)d_in[6];
    float* out = (float*)d_out;

    char* ws = (char*)d_ws;
    unsigned* usf8   = (unsigned*)(ws + 0);
    bf16*     usb    = (bf16*)(ws + 25600000);
    int*      packed = (int*)(ws + 51600000);        // 768*2560*4 = 7864320
    int*      gcur   = (int*)(ws + 59464320);        // 3072
    bf16*     Wb     = (bf16*)(ws + 59467392);       // 65536 (ends 59532928)

    hipMemsetAsync(gcur, 0, NBKT * sizeof(int), stream);
    prepscat_kernel<<<NBLKE + NCVT, 512, 0, stream>>>(us, usb, usf8, src, dst, gcur, packed,
                                                      Wself, Wneigh, Wb);
    sortfused_kernel<<<NBKT, 512, 0, stream>>>(usf8, usb, packed, gcur, Wb, bself, bneigh, out);
}

// Round 17
// 100.422 us; speedup vs baseline: 2.6223x; 2.6223x over previous
//
#include <hip/hip_runtime.h>

#define KN 100000
#define KE 1600000
#define KD 128
#define NBKT 768    // node buckets: 3 * 256 CUs, all co-resident at 3 blocks/CU
#define NPB 131     // nodes per bucket: 768*131 = 100608 >= 100000; fits 8 bits
#define NBLKE 391   // edge blocks of EPB (scatter role)
#define NCVT 782    // convert-role blocks
#define EPB 4096
#define SRTCAP 2560 // fixed slot per bucket (mean 2083, ~10 sigma headroom)

typedef __bf16 bf16;
typedef __attribute__((ext_vector_type(8))) __bf16 bf16x8;
typedef __attribute__((ext_vector_type(4))) __bf16 bf16x4;
typedef __attribute__((ext_vector_type(4))) float f32x4;
typedef __attribute__((ext_vector_type(2))) float f32x2;

// ---------------- ws layout (bytes) ----------------
// usf8   @ 0        : KN*128 fp8 (12.8 MB)
// usb    @ 25600000 : KN*128 bf16 (25.6 MB)
// packed @ 51600000 : NBKT*SRTCAP i32 (7.86 MB), fixed slot per bucket
// gcur   @ 59464320 : NBKT i32
// Wb     @ 59467392 : 128*256 bf16 (64 KB), j-major [W_self|W_neigh]

__device__ inline unsigned enc_fp8x4(float4 v) {
    int r = 0;
    r = __builtin_amdgcn_cvt_pk_fp8_f32(v.x, v.y, r, false);
    r = __builtin_amdgcn_cvt_pk_fp8_f32(v.z, v.w, r, true);
    return (unsigned)r;
}
template <bool HI>
__device__ inline f32x2 dec_fp8x2(unsigned u) {
    return __builtin_amdgcn_cvt_pk_f32_fp8((int)u, HI);
}

// Heterogeneous grid: blocks [0,391) scatter edges into fixed bucket slots;
// blocks [391,1173) stream-convert us -> usb (bf16) + usf8 (fp8) (+ Wb slice).
__launch_bounds__(512)
__global__ void prepscat_kernel(const float* __restrict__ us, bf16* __restrict__ usb,
                                unsigned* __restrict__ usf8, const int* __restrict__ src,
                                const int* __restrict__ dst, int* __restrict__ gcur,
                                int* __restrict__ packed, const float* __restrict__ Ws,
                                const float* __restrict__ Wn, bf16* __restrict__ Wb) {
    const int t = threadIdx.x, bb = blockIdx.x;
    if (bb >= NBLKE) {
        // ---- convert path (cb = 0..781) ----
        const int cb = bb - NBLKE;
        int wi = cb * 512 + t;  // W: 32768 elems over first 64 convert blocks
        if (wi < KD * 256) {
            int j = wi >> 8, k = wi & 255;
            float v = (k < KD) ? Ws[j * KD + k] : Wn[j * KD + (k - KD)];
            Wb[wi] = (bf16)v;
        }
        for (int i = cb * 512 + t; i < KN * KD / 4; i += NCVT * 512) {
            float4 v = reinterpret_cast<const float4*>(us)[i];
            bf16x4 o = {(bf16)v.x, (bf16)v.y, (bf16)v.z, (bf16)v.w};
            reinterpret_cast<bf16x4*>(usb)[i] = o;
            usf8[i] = enc_fp8x4(v);
        }
        return;
    }
    // ---- scatter path (b = 0..390) ----
    const int b = bb;
    __shared__ int h[NBKT];
    __shared__ int base[NBKT];
    for (int j = t; j < NBKT; j += 512) h[j] = 0;
    __syncthreads();
    const int e0 = b * EPB;
    int sv[8];
#pragma unroll
    for (int i = 0; i < 8; ++i) {
        int e = e0 + i * 512 + t;
        sv[i] = (e < KE) ? src[e] : -1;
        if (sv[i] >= 0) atomicAdd(&h[(unsigned)sv[i] / NPB], 1);
    }
    __syncthreads();
    for (int j = t; j < NBKT; j += 512) {
        int c = h[j];
        base[j] = (c > 0) ? (j * SRTCAP + atomicAdd(&gcur[j], c)) : 0;
        h[j] = 0;  // reuse as scatter cursor
    }
    __syncthreads();
#pragma unroll
    for (int i = 0; i < 8; ++i) {
        if (sv[i] >= 0) {
            int e = e0 + i * 512 + t;
            int d = dst[e];
            unsigned j = (unsigned)sv[i] / NPB;
            int sl = sv[i] - (int)j * NPB;
            int r = atomicAdd(&h[j], 1);
            int p = base[j] + r;
            if (p < (int)(j + 1) * SRTCAP) packed[p] = (d << 8) | sl;
        }
    }
}

// One block (512 thr) per 131-node bucket.
// phase 1: LDS counting-sort by src_low (packed read once into regs)
// phase 2: fp8 gather-aggregate (8-edge unroll: 4 outstanding 16B loads/lane
//          — the VGPR-budget optimum; 16-edge spills at 6 waves/SIMD, R16)
// phase 3: MFMA gemm, A-self direct from global, A-mean from swizzled LDS.
__launch_bounds__(512, 6)
__global__ void sortfused_kernel(const unsigned* __restrict__ usf8,
                                 const bf16* __restrict__ usb,
                                 const int* __restrict__ packed,
                                 const int* __restrict__ gcur,
                                 const bf16* __restrict__ Wb,
                                 const float* __restrict__ b_self,
                                 const float* __restrict__ b_neigh,
                                 float* __restrict__ out) {
    __shared__ bf16 meanls[NPB * 128];   // 33536 B, granule-swizzled
    __shared__ float flls[NPB];
    __shared__ int srt[SRTCAP];          // 10240 B
    __shared__ int h[132], scn[132], off[132], cur[132];

    const int t = threadIdx.x, b = blockIdx.x;
    const int n0 = b * NPB;
    const int E0 = b * SRTCAP;
    int E = gcur[b];
    if (E > SRTCAP) E = SRTCAP;

    // ---------- phase 1: counting sort (packed read once into regs) ----------
    if (t < NPB) { h[t] = 0; cur[t] = 0; }
    __syncthreads();
    int v0 = -1, v1 = -1, v2 = -1, v3 = -1, v4 = -1;
    if (t < E) v0 = packed[E0 + t];
    if (t + 512 < E) v1 = packed[E0 + t + 512];
    if (t + 1024 < E) v2 = packed[E0 + t + 1024];
    if (t + 1536 < E) v3 = packed[E0 + t + 1536];
    if (t + 2048 < E) v4 = packed[E0 + t + 2048];
    if (v0 >= 0) atomicAdd(&h[v0 & 255], 1);
    if (v1 >= 0) atomicAdd(&h[v1 & 255], 1);
    if (v2 >= 0) atomicAdd(&h[v2 & 255], 1);
    if (v3 >= 0) atomicAdd(&h[v3 & 255], 1);
    if (v4 >= 0) atomicAdd(&h[v4 & 255], 1);
    __syncthreads();
    if (t < NPB) scn[t] = h[t];
    __syncthreads();
    for (int o2 = 1; o2 < NPB; o2 <<= 1) {
        int x = 0;
        if (t < NPB && t >= o2) x = scn[t - o2];
        __syncthreads();
        if (t < NPB) scn[t] += x;
        __syncthreads();
    }
    if (t < NPB) off[t] = scn[t] - h[t];
    __syncthreads();
#define SCAT(vk)                                             \
    if (vk >= 0) {                                           \
        int sl_ = vk & 255;                                  \
        int r_ = atomicAdd(&cur[sl_], 1);                    \
        int p_ = off[sl_] + r_;                              \
        if (p_ < SRTCAP) srt[p_] = vk >> 8;                  \
    }
    SCAT(v0)
    SCAT(v1)
    SCAT(v2)
    SCAT(v3)
    SCAT(v4)
#undef SCAT
    __syncthreads();

    // ---------- phase 2: gather-aggregate into swizzled meanls ----------
    const int lane = t & 63, w = t >> 6;           // 8 waves
    const int gid = (w << 2) + ((lane >> 4) & 3);  // 16-lane group 0..31
    const int sub = (lane >> 3) & 1;               // edge-slot parity
    const int sl = lane & 7;                       // 16B chunk: cols sl*16..+15
    const uint4* __restrict__ u4 = reinterpret_cast<const uint4*>(usf8);

#define ACC16(Q)                                                          \
    {                                                                     \
        f32x2 p;                                                          \
        p = dec_fp8x2<false>(Q.x); a[0] += p[0];  a[1] += p[1];           \
        p = dec_fp8x2<true>(Q.x);  a[2] += p[0];  a[3] += p[1];           \
        p = dec_fp8x2<false>(Q.y); a[4] += p[0];  a[5] += p[1];           \
        p = dec_fp8x2<true>(Q.y);  a[6] += p[0];  a[7] += p[1];           \
        p = dec_fp8x2<false>(Q.z); a[8] += p[0];  a[9] += p[1];           \
        p = dec_fp8x2<true>(Q.z);  a[10] += p[0]; a[11] += p[1];          \
        p = dec_fp8x2<false>(Q.w); a[12] += p[0]; a[13] += p[1];          \
        p = dec_fp8x2<true>(Q.w);  a[14] += p[0]; a[15] += p[1];          \
    }

#pragma unroll 1
    for (int it = 0; it < 5; ++it) {
        int nl = it * 32 + gid;  // 0..159
        bool valid = (nl < NPB) && (n0 + nl < KN);
        int cnt = valid ? h[nl] : 0;
        int o = valid ? off[nl] : 0;
        float a[16];
#pragma unroll
        for (int j = 0; j < 16; ++j) a[j] = 0.f;
        int e = 0;
        for (; e + 8 <= cnt; e += 8) {
            int d0 = srt[o + e + sub];
            int d1 = srt[o + e + 2 + sub];
            int d2 = srt[o + e + 4 + sub];
            int d3 = srt[o + e + 6 + sub];
            uint4 q0 = u4[(size_t)d0 * 8 + sl];
            uint4 q1 = u4[(size_t)d1 * 8 + sl];
            uint4 q2 = u4[(size_t)d2 * 8 + sl];
            uint4 q3 = u4[(size_t)d3 * 8 + sl];
            ACC16(q0);
            ACC16(q1);
            ACC16(q2);
            ACC16(q3);
        }
        for (; e < cnt; e += 2) {
            if (e + sub < cnt) {
                int d0 = srt[o + e + sub];
                uint4 q0 = u4[(size_t)d0 * 8 + sl];
                ACC16(q0);
            }
        }
#pragma unroll
        for (int j = 0; j < 16; ++j) a[j] += __shfl_xor(a[j], 8);
        if ((nl < NPB) && sub == 0) {
            float rc = (cnt > 0) ? 1.0f / (float)cnt : 0.0f;
            bf16x8 o0, o1;
#pragma unroll
            for (int j = 0; j < 8; ++j) {
                o0[j] = (bf16)(a[j] * rc);
                o1[j] = (bf16)(a[j + 8] * rc);
            }
            int G0 = (sl * 2) ^ (nl & 7);
            int G1 = (sl * 2 + 1) ^ (nl & 7);
            *reinterpret_cast<bf16x8*>(&meanls[nl * 128 + (G0 << 3)]) = o0;
            *reinterpret_cast<bf16x8*>(&meanls[nl * 128 + (G1 << 3)]) = o1;
            if (sl == 0) flls[nl] = (cnt > 0) ? 1.0f : 0.0f;
        }
    }
#undef ACC16
    __syncthreads();

    // ---------- phase 3: MFMA gemm ----------
    const int lr = lane & 15;
    const int g = lane >> 4;
    bf16x8 Bf[8];
    {
        const bf16* wp = Wb + (size_t)(w * 16 + lr) * 256 + g * 8;
#pragma unroll
        for (int ch = 0; ch < 8; ++ch) Bf[ch] = *reinterpret_cast<const bf16x8*>(wp + ch * 32);
    }
    const float bs = b_self[w * 16 + lr];
    const float bn = b_neigh[w * 16 + lr];

#pragma unroll 1
    for (int rt = 0; rt < 9; ++rt) {
        f32x4 acc = {0.f, 0.f, 0.f, 0.f};
        const int arow = rt * 16 + lr;
        const int mrow = (arow < NPB) ? arow : (NPB - 1);
        int na = n0 + arow;
        if (na >= KN) na = KN - 1;
        const bf16* apu = usb + (size_t)na * KD + g * 8;
        const int mswz = mrow & 7;
        const bf16* apm = &meanls[mrow * 128];
#pragma unroll
        for (int ch = 0; ch < 4; ++ch) {
            bf16x8 af = *reinterpret_cast<const bf16x8*>(apu + ch * 32);
            acc = __builtin_amdgcn_mfma_f32_16x16x32_bf16(af, Bf[ch], acc, 0, 0, 0);
        }
#pragma unroll
        for (int ch = 0; ch < 4; ++ch) {
            int G = (g + 4 * ch) ^ mswz;
            bf16x8 af = *reinterpret_cast<const bf16x8*>(apm + (G << 3));
            acc = __builtin_amdgcn_mfma_f32_16x16x32_bf16(af, Bf[ch + 4], acc, 0, 0, 0);
        }
#pragma unroll
        for (int r = 0; r < 4; ++r) {
            int rowg = rt * 16 + g * 4 + r;
            int n = n0 + rowg;
            if (rowg < NPB && n < KN) {
                float f = flls[rowg];
                out[(size_t)n * KD + w * 16 + lr] = fmaxf(acc[r] + bs + f * bn, 0.0f);
            }
        }
    }
}

extern "C" void kernel_launch(void* const* d_in, const int* in_sizes, int n_in,
                              void* d_out, int out_size, void* d_ws, size_t ws_size,
                              hipStream_t stream) {
    const float* us     = (const float*)d_in[0];
    const int*   src    = (const int*)d_in[1];
    const int*   dst    = (const int*)d_in[2];
    const float* Wself  = (const float*)d_in[3];
    const float* bself  = (const float*)d_in[4];
    const float* Wneigh = (const float*)d_in[5];
    const float* bneigh = (const float*)d_in[6];
    float* out = (float*)d_out;

    char* ws = (char*)d_ws;
    unsigned* usf8   = (unsigned*)(ws + 0);
    bf16*     usb    = (bf16*)(ws + 25600000);
    int*      packed = (int*)(ws + 51600000);        // 768*2560*4 = 7864320
    int*      gcur   = (int*)(ws + 59464320);        // 3072
    bf16*     Wb     = (bf16*)(ws + 59467392);       // 65536 (ends 59532928)

    hipMemsetAsync(gcur, 0, NBKT * sizeof(int), stream);
    prepscat_kernel<<<NBLKE + NCVT, 512, 0, stream>>>(us, usb, usf8, src, dst, gcur, packed,
                                                      Wself, Wneigh, Wb);
    sortfused_kernel<<<NBKT, 512, 0, stream>>>(usf8, usb, packed, gcur, Wb, bself, bneigh, out);
}